// Round 6
// baseline (2052.517 us; speedup 1.0000x reference)
//
#include <hip/hip_runtime.h>

#define BB 2
#define SS 2048
#define DDIM 1024
#define HH 16
#define DEPTH 64
#define QKVW (3*DDIM)   // 3072, row stride of the per-batch qkv f32 buffer

typedef unsigned short u16;
typedef unsigned int u32;

__device__ __forceinline__ float bf2f(u16 v){ union{u32 u; float f;} z; z.u=((u32)v)<<16; return z.f; }
// dtype-flex load: element i of tensor p, which is bf16 if bf else f32.
__device__ __forceinline__ float ldf(const void* p, size_t i, bool bf){
  return bf ? bf2f(((const u16*)p)[i]) : ((const float*)p)[i];
}

#define NEG_BIG (-1e30f)

// ---------------- dtype sniffer ----------------
// One block. Looks at x's first 256 32-bit words. If x is bf16, the low 16 bits
// of each word are a bf16 value of ~N(0,1): exponent field in [100,140] nearly
// always. If x is f32, the low 16 bits are mantissa noise: ~16% hit rate.
// (Round-5 result: flag=0 — inputs are f32. Kept as cheap insurance.)
__global__ void sniff_k(const u32* __restrict__ x, u32* __restrict__ flag){
  __shared__ int cnt[256];
  const int tid = threadIdx.x;
  u32 w = x[tid];
  int e = (int)((w >> 7) & 0xFFu);
  cnt[tid] = (e >= 100 && e <= 140) ? 1 : 0;
  __syncthreads();
  for (int s = 128; s > 0; s >>= 1){
    if (tid < s) cnt[tid] += cnt[tid + s];
    __syncthreads();
  }
  if (tid == 0) flag[0] = (cnt[0] > 128) ? 1u : 0u;
}

// ---------------- QKV GEMM (f32 vector): qkv[2048,3072] = x_b @ W + b ----------------
// 64x64 tile, BK=16, 256 threads, 4x4 micro-tile. Dtype-flex input loads.
__global__ __launch_bounds__(256,2) void gemm_qkv_k(
    const void* __restrict__ X, size_t xoff,
    const void* __restrict__ W, const void* __restrict__ bq,
    const u32* __restrict__ flag, float* __restrict__ qkv)
{
  const bool bf = (flag[0] != 0u);
  __shared__ float As[64][17];
  __shared__ float Bs[16][65];
  const int tid = threadIdx.x;
  const int m0 = blockIdx.x<<6, n0 = blockIdx.y<<6;
  const int tr = tid>>4, tc = tid&15;

  float acc[4][4];
  #pragma unroll
  for (int i=0;i<4;i++)
    #pragma unroll
    for (int j=0;j<4;j++) acc[i][j] = 0.f;

  for (int k0=0;k0<DDIM;k0+=16){
    __syncthreads();
    for (int c=tid;c<1024;c+=256){
      int mm=c>>4, kk=c&15;
      As[mm][kk] = ldf(X, xoff + (size_t)(m0+mm)*DDIM + k0+kk, bf);
    }
    for (int c=tid;c<1024;c+=256){
      int kk=c>>6, nn=c&63;
      Bs[kk][nn] = ldf(W, (size_t)(k0+kk)*QKVW + n0+nn, bf);
    }
    __syncthreads();
    #pragma unroll
    for (int kk=0;kk<16;kk++){
      float a[4], b[4];
      #pragma unroll
      for (int i=0;i<4;i++) a[i] = As[(tr<<2)+i][kk];
      #pragma unroll
      for (int j=0;j<4;j++) b[j] = Bs[kk][(tc<<2)+j];
      #pragma unroll
      for (int i=0;i<4;i++)
        #pragma unroll
        for (int j=0;j<4;j++) acc[i][j] = fmaf(a[i], b[j], acc[i][j]);
    }
  }

  #pragma unroll
  for (int j=0;j<4;j++){
    int n = n0 + (tc<<2) + j;
    float bv = ldf(bq, (size_t)n, bf);
    #pragma unroll
    for (int i=0;i<4;i++)
      qkv[(size_t)(m0 + (tr<<2) + i)*QKVW + n] = acc[i][j] + bv;
  }
}

// ---------------- flash attention, all-f32, per (h, 16-row q-tile) ----------------
// qkv row layout per s: [h: q0..63 | k0..63 | v0..63] stride 192 per head.
// Output overwrites the Q slots (sole reader of a Q slot is this very block).
__global__ __launch_bounds__(256,2) void attn_k(float* __restrict__ qkv)
{
  __shared__ float qs[16][64];        // q rows, pre-scaled by 1/8
  __shared__ float Vsf[64][65];       // V tile, +1 pad
  __shared__ float ps[4][64][4];      // [wave][kv j][row], scalar f32 only

  const int tid = threadIdx.x, w = tid>>6, lane = tid&63;
  const int h = blockIdx.y;
  const int r0 = blockIdx.x<<4;
  const int hb = h*192;

  {
    int rl = tid>>4, d4 = (tid&15)<<2;
    float4 qv = *(const float4*)(qkv + (size_t)(r0+rl)*QKVW + hb + d4);
    qs[rl][d4+0] = qv.x * 0.125f;
    qs[rl][d4+1] = qv.y * 0.125f;
    qs[rl][d4+2] = qv.z * 0.125f;
    qs[rl][d4+3] = qv.w * 0.125f;
  }

  float m_r[4], l_r[4], o_r[4];
  #pragma unroll
  for (int r=0;r<4;r++){ m_r[r] = NEG_BIG; l_r[r] = 0.f; o_r[r] = 0.f; }

  const int T = (r0>>6) + 1;
  for (int t=0;t<T;t++){
    __syncthreads();                  // prior tile's reads done (also covers qs staging)
    for (int c = tid; c < 1024; c += 256){
      int j = c>>4, d4 = (c&15)<<2;
      float4 vv = *(const float4*)(qkv + (size_t)((t<<6)+j)*QKVW + hb + 128 + d4);
      Vsf[j][d4+0] = vv.x;
      Vsf[j][d4+1] = vv.y;
      Vsf[j][d4+2] = vv.z;
      Vsf[j][d4+3] = vv.w;
    }
    const int jj = (t<<6) + lane;     // this lane's kv row (< S always)
    float4 k4[16];
    {
      const float* kp = qkv + (size_t)jj*QKVW + hb + 64;
      #pragma unroll
      for (int c=0;c<16;c++) k4[c] = *(const float4*)(kp + (c<<2));
    }
    __syncthreads();

    #pragma unroll
    for (int r=0;r<4;r++){
      const int rl = (w<<2) + r;
      const int iq = r0 + rl;
      const bool live = (jj <= iq);
      float a0=0.f, a1=0.f, a2=0.f, a3=0.f;
      #pragma unroll
      for (int c=0;c<16;c++){
        a0 = fmaf(k4[c].x, qs[rl][(c<<2)+0], a0);
        a1 = fmaf(k4[c].y, qs[rl][(c<<2)+1], a1);
        a2 = fmaf(k4[c].z, qs[rl][(c<<2)+2], a2);
        a3 = fmaf(k4[c].w, qs[rl][(c<<2)+3], a3);
      }
      const float s  = (a0+a1)+(a2+a3);
      const float sm = live ? s : NEG_BIG;
      float mt = sm;
      #pragma unroll
      for (int off=32; off; off>>=1) mt = fmaxf(mt, __shfl_xor(mt, off));
      const float mnew  = fmaxf(m_r[r], mt);      // finite from tile 0 (lane 0 always live)
      const float alpha = __expf(m_r[r] - mnew);
      const float p     = live ? __expf(s - mnew) : 0.f;
      ps[w][lane][r] = p;
      float psum = p;
      #pragma unroll
      for (int off=32; off; off>>=1) psum += __shfl_xor(psum, off);
      l_r[r] = l_r[r]*alpha + psum;
      m_r[r] = mnew;
      o_r[r] *= alpha;
    }

    __syncthreads();                  // ps stores visible before PV reads

    #pragma unroll 4
    for (int j=0;j<64;j++){
      const float v = Vsf[j][lane];
      o_r[0] = fmaf(ps[w][j][0], v, o_r[0]);
      o_r[1] = fmaf(ps[w][j][1], v, o_r[1]);
      o_r[2] = fmaf(ps[w][j][2], v, o_r[2]);
      o_r[3] = fmaf(ps[w][j][3], v, o_r[3]);
    }
  }

  #pragma unroll
  for (int r=0;r<4;r++){
    const int rl = (w<<2) + r;
    qkv[(size_t)(r0+rl)*QKVW + hb + lane] = o_r[r] / fmaxf(l_r[r], 1e-30f);
  }
}

// ---------------- output projection (f32 vector): out_b = At @ W_out + b_out ----------------
// At lives in the Q slots of qkv: At(m, h*64+d) = qkv[m*3072 + h*192 + d].
// OUTPUT IS f32 (reference returns float32; harness: "else float*").
__global__ __launch_bounds__(256,2) void gemm_out_k(
    const float* __restrict__ Aq, const void* __restrict__ Wo,
    const void* __restrict__ bo, const u32* __restrict__ flag,
    float* __restrict__ out)
{
  const bool bf = (flag[0] != 0u);
  __shared__ float As[64][17];
  __shared__ float Bs[16][65];
  const int tid = threadIdx.x;
  const int m0 = blockIdx.x<<6, n0 = blockIdx.y<<6;
  const int tr = tid>>4, tc = tid&15;

  float acc[4][4];
  #pragma unroll
  for (int i=0;i<4;i++)
    #pragma unroll
    for (int j=0;j<4;j++) acc[i][j] = 0.f;

  for (int k0=0;k0<DDIM;k0+=16){
    __syncthreads();
    {
      int mm = tid>>2, kq = (tid&3)<<2;
      int kk = k0 + kq;
      float4 av = *(const float4*)(Aq + (size_t)(m0+mm)*QKVW + (kk>>6)*192 + (kk&63));
      As[mm][kq+0] = av.x;
      As[mm][kq+1] = av.y;
      As[mm][kq+2] = av.z;
      As[mm][kq+3] = av.w;
    }
    for (int c = tid; c < 1024; c += 256){
      int kk = c>>6, nn = c&63;
      Bs[kk][nn] = ldf(Wo, (size_t)(k0+kk)*DDIM + n0 + nn, bf);
    }
    __syncthreads();
    #pragma unroll
    for (int kk=0;kk<16;kk++){
      float a[4], b[4];
      #pragma unroll
      for (int i=0;i<4;i++) a[i] = As[(tr<<2)+i][kk];
      #pragma unroll
      for (int j=0;j<4;j++) b[j] = Bs[kk][(tc<<2)+j];
      #pragma unroll
      for (int i=0;i<4;i++)
        #pragma unroll
        for (int j=0;j<4;j++) acc[i][j] = fmaf(a[i], b[j], acc[i][j]);
    }
  }

  #pragma unroll
  for (int j=0;j<4;j++){
    int n = n0 + (tc<<2) + j;
    float bv = ldf(bo, (size_t)n, bf);
    #pragma unroll
    for (int i=0;i<4;i++)
      out[(size_t)(m0 + (tr<<2) + i)*DDIM + n] = acc[i][j] + bv;   // f32 store
  }
}

extern "C" void kernel_launch(void* const* d_in, const int* in_sizes, int n_in,
                              void* d_out, int out_size, void* d_ws, size_t ws_size,
                              hipStream_t stream)
{
  // input order per reference: x, mask, W_qkv, b_qkv, W_out, b_out
  int ix = 0, iw = 2, ibq = 3, iwo = 4, ibo = 5;
  if (n_in == 5){ iw = 1; ibq = 2; iwo = 3; ibo = 4; }  // defensive: mask dropped
  const void* x  = d_in[ix];
  const void* Wq = d_in[iw];
  const void* bq = d_in[ibq];
  const void* Wo = d_in[iwo];
  const void* bo = d_in[ibo];
  float* out = (float*)d_out;   // reference output dtype is float32

  u32*   flag = (u32*)d_ws;                       // 256 B reserved
  float* qkv  = (float*)((char*)d_ws + 256);      // [2048, 3072] f32, reused per batch

  sniff_k<<<1, 256, 0, stream>>>((const u32*)x, flag);

  for (int b=0;b<BB;b++){
    size_t xoff = (size_t)b*SS*DDIM;              // element offset (dtype-agnostic)
    float* outb = out + (size_t)b*SS*DDIM;
    gemm_qkv_k<<<dim3(SS/64, QKVW/64), 256, 0, stream>>>(x, xoff, Wq, bq, flag, qkv);
    attn_k    <<<dim3(SS/16, HH),      256, 0, stream>>>(qkv);
    gemm_out_k<<<dim3(SS/64, DDIM/64), 256, 0, stream>>>(qkv, Wo, bo, flag, outb);
  }
}

// Round 7
// 352.557 us; speedup vs baseline: 5.8218x; 5.8218x over previous
//
#include <hip/hip_runtime.h>

#define BB 2
#define SS 2048
#define DDIM 1024
#define HH 16
#define DEPTH 64
#define QKVN (3*DDIM)

typedef unsigned short u16;
typedef unsigned int u32;
typedef __attribute__((ext_vector_type(8))) short bf16x8;
typedef __attribute__((ext_vector_type(4))) float f32x4;

__device__ __forceinline__ u16 f2bf(float f){
  union{float f; u32 u;} z; z.f=f;
  u32 r = z.u + 0x7fffu + ((z.u>>16)&1u);
  return (u16)(r>>16);
}
#define NEG_BIG (-1e30f)

// ---------------- transpose+convert f32 [R,C] -> bf16 [C,R] ----------------
__global__ void convT_k(const float* __restrict__ in, u16* __restrict__ out, int R, int C){
  __shared__ float tile[32][33];
  int c0 = blockIdx.x<<5, r0 = blockIdx.y<<5;
  int tx = threadIdx.x, ty = threadIdx.y;
  for (int i=ty;i<32;i+=8) tile[i][tx] = in[(size_t)(r0+i)*C + c0+tx];
  __syncthreads();
  for (int i=ty;i<32;i+=8) out[(size_t)(c0+i)*R + r0+tx] = f2bf(tile[tx][i]);
}

// ---------------- convert f32 -> bf16 flat (x per batch) ----------------
__global__ void convX_k(const float* __restrict__ in, u16* __restrict__ out){
  size_t i = ((size_t)blockIdx.x*256 + threadIdx.x) * 8;
  float4 a = *(const float4*)(in + i);
  float4 b = *(const float4*)(in + i + 4);
  ushort4 lo = { f2bf(a.x), f2bf(a.y), f2bf(a.z), f2bf(a.w) };
  ushort4 hi = { f2bf(b.x), f2bf(b.y), f2bf(b.z), f2bf(b.w) };
  *(ushort4*)(out + i)     = lo;
  *(ushort4*)(out + i + 4) = hi;
}

// ---------------- QKV GEMM (m93 bf16 MFMA): [2048,1024]@[1024,3072]^T ----------------
// Epilogue splits into Qb[h][s][64] (x0.125), Kb[h][s][64], Vt[h][d][s] (transposed).
__global__ __launch_bounds__(256,2) void gemm_qkv_k(
    const u16* __restrict__ A, const u16* __restrict__ Bt,
    const float* __restrict__ bias,
    u16* __restrict__ Qb, u16* __restrict__ Kb, u16* __restrict__ Vt)
{
  const int K = DDIM;
  __shared__ __align__(16) u16 As[128*32];
  __shared__ __align__(16) u16 Bs[128*32];
  const int tid = threadIdx.x;
  const int m0 = blockIdx.x<<7, n0 = blockIdx.y<<7;
  const int w = tid>>6, lane = tid&63, q = lane>>4, ln = lane&15;
  const int wr = (w>>1)<<6, wc = (w&1)<<6;

  f32x4 acc[4][4];
  #pragma unroll
  for (int i=0;i<4;i++)
    #pragma unroll
    for (int j=0;j<4;j++) acc[i][j] = (f32x4){0.f,0.f,0.f,0.f};

  for (int k0=0;k0<K;k0+=32){
    {
      int c = tid, row = c>>2, off = (c&3)<<3;
      *(uint4*)&As[(row<<5)+off] = *(const uint4*)&A [(size_t)(m0+row)*K + k0 + off];
      *(uint4*)&Bs[(row<<5)+off] = *(const uint4*)&Bt[(size_t)(n0+row)*K + k0 + off];
      c = tid + 256; row = c>>2; off = (c&3)<<3;
      *(uint4*)&As[(row<<5)+off] = *(const uint4*)&A [(size_t)(m0+row)*K + k0 + off];
      *(uint4*)&Bs[(row<<5)+off] = *(const uint4*)&Bt[(size_t)(n0+row)*K + k0 + off];
    }
    __syncthreads();
    bf16x8 af[4], bfr[4];
    #pragma unroll
    for (int i=0;i<4;i++) af[i]  = *(const bf16x8*)&As[((wr + (i<<4) + ln)<<5) + (q<<3)];
    #pragma unroll
    for (int j=0;j<4;j++) bfr[j] = *(const bf16x8*)&Bs[((wc + (j<<4) + ln)<<5) + (q<<3)];
    #pragma unroll
    for (int i=0;i<4;i++)
      #pragma unroll
      for (int j=0;j<4;j++)
        acc[i][j] = __builtin_amdgcn_mfma_f32_16x16x32_bf16(af[i], bfr[j], acc[i][j], 0, 0, 0);
    __syncthreads();
  }

  #pragma unroll
  for (int i=0;i<4;i++){
    const int sb = m0 + wr + (i<<4) + (q<<2);          // base s for the 4 rows
    #pragma unroll
    for (int j=0;j<4;j++){
      const int n = n0 + wc + (j<<4) + ln;
      const int h = n / 192;
      const int rr = n - h*192;                        // uniform per (i,j) 16-col block
      const float bv = bias[n];
      if (rr < 64){                                    // Q, scaled by 1/8
        u16* dst = Qb + (size_t)h*SS*DEPTH + rr;
        #pragma unroll
        for (int r=0;r<4;r++) dst[(size_t)(sb+r)*DEPTH] = f2bf((acc[i][j][r] + bv)*0.125f);
      } else if (rr < 128){                            // K
        u16* dst = Kb + (size_t)h*SS*DEPTH + (rr-64);
        #pragma unroll
        for (int r=0;r<4;r++) dst[(size_t)(sb+r)*DEPTH] = f2bf(acc[i][j][r] + bv);
      } else {                                         // V transposed: Vt[h][d][s]
        ushort4 pv = { f2bf(acc[i][j][0] + bv), f2bf(acc[i][j][1] + bv),
                       f2bf(acc[i][j][2] + bv), f2bf(acc[i][j][3] + bv) };
        *(ushort4*)(Vt + ((size_t)h*DEPTH + (rr-128))*SS + sb) = pv;
      }
    }
  }
}

// ---------------- MFMA flash attention ----------------
// Block = 64 q-rows of one head; 4 waves x 16 rows. Q A-frags in registers.
// Per kv tile (64): QK^T (bt-form vs Ks), register online-softmax, P->bf16 via
// LDS ps (layout transform, m120 pattern), PV (bt-form vs VsT = V^T tile).
// Output overwrites this block's own Qb rows (sole reader; regs loaded first).
__global__ __launch_bounds__(256,2) void attn_k(
    u16* __restrict__ Qb, const u16* __restrict__ Kb, const u16* __restrict__ Vt)
{
  __shared__ __align__(16) u16 Ks[64*64];      // K tile [j][d]
  __shared__ __align__(16) u16 VsT[64*72];     // V^T tile [d][j], stride 72
  __shared__ __align__(16) u16 ps[4][16*72];   // per-wave P [m][j], stride 72

  const int tid = threadIdx.x, w = tid>>6, lane = tid&63, q = lane>>4, ln = lane&15;
  const int h = blockIdx.y;
  const int r0 = blockIdx.x<<6;
  const size_t kbase = (size_t)h*SS*DEPTH;     // Kb/Qb per-head base
  const size_t vbase = (size_t)h*DEPTH*SS;     // Vt per-head base

  // Q A-frags for this wave's 16 rows, both k-steps — once, in registers.
  bf16x8 qf[2];
  #pragma unroll
  for (int ks=0;ks<2;ks++)
    qf[ks] = *(const bf16x8*)(Qb + kbase + (size_t)(r0 + (w<<4) + ln)*DEPTH + (ks<<5) + (q<<3));

  f32x4 o[4];
  #pragma unroll
  for (int nt=0;nt<4;nt++) o[nt] = (f32x4){0.f,0.f,0.f,0.f};
  float m_r[4], l_r[4];
  #pragma unroll
  for (int r=0;r<4;r++){ m_r[r] = NEG_BIG; l_r[r] = 0.f; }

  const int T = blockIdx.x + 1;
  for (int t=0;t<T;t++){
    __syncthreads();                           // prior tile's Ks/VsT/ps reads done
    #pragma unroll
    for (int p=0;p<2;p++){
      int e = (p*256 + tid)*8;
      int j = e>>6, d = e&63;
      *(uint4*)&Ks[j*64 + d]  = *(const uint4*)(Kb + kbase + (size_t)((t<<6)+j)*DEPTH + d);
      int d2 = e>>6, j2 = e&63;
      *(uint4*)&VsT[d2*72 + j2] = *(const uint4*)(Vt + vbase + (size_t)d2*SS + (t<<6) + j2);
    }
    __syncthreads();

    // QK^T
    f32x4 sc[4];
    #pragma unroll
    for (int jt=0;jt<4;jt++) sc[jt] = (f32x4){0.f,0.f,0.f,0.f};
    #pragma unroll
    for (int ks=0;ks<2;ks++){
      #pragma unroll
      for (int jt=0;jt<4;jt++){
        bf16x8 kf = *(const bf16x8*)&Ks[((jt<<4)+ln)*64 + (ks<<5) + (q<<3)];
        sc[jt] = __builtin_amdgcn_mfma_f32_16x16x32_bf16(qf[ks], kf, sc[jt], 0, 0, 0);
      }
    }

    // causal mask on diagonal tile (cols t*64+jt*16+ln vs rows r0+w*16+q*4+reg)
    if (t == T-1){
      const int rowb = r0 + (w<<4) + (q<<2);
      #pragma unroll
      for (int jt=0;jt<4;jt++){
        const int col = (t<<6) + (jt<<4) + ln;
        #pragma unroll
        for (int r=0;r<4;r++)
          if (col > rowb + r) sc[jt][r] = NEG_BIG;
      }
    }

    // online softmax per row (row lives on 16 lanes sharing quad q)
    float alpha_r[4];
    #pragma unroll
    for (int r=0;r<4;r++){
      float mt = fmaxf(fmaxf(sc[0][r], sc[1][r]), fmaxf(sc[2][r], sc[3][r]));
      #pragma unroll
      for (int off=1; off<16; off<<=1) mt = fmaxf(mt, __shfl_xor(mt, off));
      const float mnew = fmaxf(m_r[r], mt);
      alpha_r[r] = __expf(m_r[r] - mnew);
      float p0 = __expf(sc[0][r]-mnew), p1 = __expf(sc[1][r]-mnew);
      float p2 = __expf(sc[2][r]-mnew), p3 = __expf(sc[3][r]-mnew);
      const int mrow = (q<<2) + r;
      ps[w][mrow*72 +      ln] = f2bf(p0);
      ps[w][mrow*72 + 16 + ln] = f2bf(p1);
      ps[w][mrow*72 + 32 + ln] = f2bf(p2);
      ps[w][mrow*72 + 48 + ln] = f2bf(p3);
      float psum = (p0+p1)+(p2+p3);
      #pragma unroll
      for (int off=1; off<16; off<<=1) psum += __shfl_xor(psum, off);
      l_r[r] = l_r[r]*alpha_r[r] + psum;
      m_r[r] = mnew;
    }
    #pragma unroll
    for (int nt=0;nt<4;nt++)
      #pragma unroll
      for (int r=0;r<4;r++) o[nt][r] *= alpha_r[r];

    __syncthreads();                           // ps visible/ordered before PV reads

    // PV
    #pragma unroll
    for (int ks=0;ks<2;ks++){
      bf16x8 pa = *(const bf16x8*)&ps[w][ln*72 + (ks<<5) + (q<<3)];
      #pragma unroll
      for (int nt=0;nt<4;nt++){
        bf16x8 vf = *(const bf16x8*)&VsT[((nt<<4)+ln)*72 + (ks<<5) + (q<<3)];
        o[nt] = __builtin_amdgcn_mfma_f32_16x16x32_bf16(pa, vf, o[nt], 0, 0, 0);
      }
    }
  }

  // epilogue: o/l -> bf16, overwrite this block's own Qb rows
  #pragma unroll
  for (int r=0;r<4;r++){
    const float rl = 1.f / fmaxf(l_r[r], 1e-30f);
    const int s = r0 + (w<<4) + (q<<2) + r;
    #pragma unroll
    for (int nt=0;nt<4;nt++)
      Qb[kbase + (size_t)s*DEPTH + (nt<<4) + ln] = f2bf(o[nt][r] * rl);
  }
}

// ---------------- out projection (m93 bf16 MFMA), A in Qb layout, f32 out ----------------
__global__ __launch_bounds__(256,2) void gemm_out_k(
    const u16* __restrict__ Aq, const u16* __restrict__ Bt,
    const float* __restrict__ bias, float* __restrict__ out)
{
  const int K = DDIM;
  __shared__ __align__(16) u16 As[128*32];
  __shared__ __align__(16) u16 Bs[128*32];
  const int tid = threadIdx.x;
  const int m0 = blockIdx.x<<7, n0 = blockIdx.y<<7;
  const int w = tid>>6, lane = tid&63, q = lane>>4, ln = lane&15;
  const int wr = (w>>1)<<6, wc = (w&1)<<6;

  f32x4 acc[4][4];
  #pragma unroll
  for (int i=0;i<4;i++)
    #pragma unroll
    for (int j=0;j<4;j++) acc[i][j] = (f32x4){0.f,0.f,0.f,0.f};

  for (int k0=0;k0<K;k0+=32){
    const size_t abase = (size_t)(k0>>6)*SS*DEPTH + (k0&63);   // Qb-layout: [h=k/64][s][k%64]
    {
      int c = tid, row = c>>2, off = (c&3)<<3;
      *(uint4*)&As[(row<<5)+off] = *(const uint4*)&Aq[abase + (size_t)(m0+row)*DEPTH + off];
      *(uint4*)&Bs[(row<<5)+off] = *(const uint4*)&Bt[(size_t)(n0+row)*K + k0 + off];
      c = tid + 256; row = c>>2; off = (c&3)<<3;
      *(uint4*)&As[(row<<5)+off] = *(const uint4*)&Aq[abase + (size_t)(m0+row)*DEPTH + off];
      *(uint4*)&Bs[(row<<5)+off] = *(const uint4*)&Bt[(size_t)(n0+row)*K + k0 + off];
    }
    __syncthreads();
    bf16x8 af[4], bfr[4];
    #pragma unroll
    for (int i=0;i<4;i++) af[i]  = *(const bf16x8*)&As[((wr + (i<<4) + ln)<<5) + (q<<3)];
    #pragma unroll
    for (int j=0;j<4;j++) bfr[j] = *(const bf16x8*)&Bs[((wc + (j<<4) + ln)<<5) + (q<<3)];
    #pragma unroll
    for (int i=0;i<4;i++)
      #pragma unroll
      for (int j=0;j<4;j++)
        acc[i][j] = __builtin_amdgcn_mfma_f32_16x16x32_bf16(af[i], bfr[j], acc[i][j], 0, 0, 0);
    __syncthreads();
  }

  #pragma unroll
  for (int i=0;i<4;i++){
    #pragma unroll
    for (int j=0;j<4;j++){
      const int n = n0 + wc + (j<<4) + ln;
      const float bv = bias[n];
      #pragma unroll
      for (int r=0;r<4;r++){
        const int mm = m0 + wr + (i<<4) + (q<<2) + r;
        out[(size_t)mm*DDIM + n] = acc[i][j][r] + bv;
      }
    }
  }
}

extern "C" void kernel_launch(void* const* d_in, const int* in_sizes, int n_in,
                              void* d_out, int out_size, void* d_ws, size_t ws_size,
                              hipStream_t stream)
{
  int ix = 0, iw = 2, ibq = 3, iwo = 4, ibo = 5;
  if (n_in == 5){ iw = 1; ibq = 2; iwo = 3; ibo = 4; }
  const float* x  = (const float*)d_in[ix];
  const float* Wq = (const float*)d_in[iw];
  const float* bq = (const float*)d_in[ibq];
  const float* Wo = (const float*)d_in[iwo];
  const float* bo = (const float*)d_in[ibo];
  float* out = (float*)d_out;

  // workspace (u16 units), total 25,165,824 B — within the round-6-proven footprint
  u16* ws  = (u16*)d_ws;
  u16* Wqt = ws;                                   // [3072,1024] bf16
  u16* Wot = Wqt + (size_t)QKVN*DDIM;              // [1024,1024] bf16 (bt form)
  u16* Qb  = Wot + (size_t)DDIM*DDIM;              // [H][S][64] bf16; attn out aliases here
  u16* Kb  = Qb  + (size_t)HH*SS*DEPTH;            // [H][S][64] bf16
  u16* Vt  = Kb  + (size_t)HH*SS*DEPTH;            // [H][64][S] bf16 (V transposed)
  u16* xb  = Vt  + (size_t)HH*SS*DEPTH;            // [2048,1024] bf16 (per batch)

  convT_k<<<dim3(QKVN/32, DDIM/32), dim3(32,8), 0, stream>>>(Wq, Wqt, DDIM, QKVN);
  convT_k<<<dim3(DDIM/32, DDIM/32), dim3(32,8), 0, stream>>>(Wo, Wot, DDIM, DDIM);

  for (int b=0;b<BB;b++){
    const float* xf = x + (size_t)b*SS*DDIM;
    float* outb = out + (size_t)b*SS*DDIM;
    convX_k   <<<dim3(SS*DDIM/2048),            256, 0, stream>>>(xf, xb);
    gemm_qkv_k<<<dim3(SS/128, QKVN/128),        256, 0, stream>>>(xb, Wqt, bq, Qb, Kb, Vt);
    attn_k    <<<dim3(SS/64, HH),               256, 0, stream>>>(Qb, Kb, Vt);
    gemm_out_k<<<dim3(SS/128, DDIM/128),        256, 0, stream>>>(Qb, Wot, bo, outb);
  }
}

// Round 8
// 253.832 us; speedup vs baseline: 8.0861x; 1.3889x over previous
//
#include <hip/hip_runtime.h>

#define BB 2
#define SS 2048
#define DDIM 1024
#define HH 16
#define DEPTH 64
#define QKVN (3*DDIM)

typedef unsigned short u16;
typedef unsigned int u32;
typedef __attribute__((ext_vector_type(8))) short bf16x8;
typedef __attribute__((ext_vector_type(4))) float f32x4;

__device__ __forceinline__ u16 f2bf(float f){
  union{float f; u32 u;} z; z.f=f;
  u32 r = z.u + 0x7fffu + ((z.u>>16)&1u);
  return (u16)(r>>16);
}
#define NEG_BIG (-1e30f)

// ---------------- transpose+convert f32 [R,C] -> bf16 [C,R] ----------------
__global__ void convT_k(const float* __restrict__ in, u16* __restrict__ out, int R, int C){
  __shared__ float tile[32][33];
  int c0 = blockIdx.x<<5, r0 = blockIdx.y<<5;
  int tx = threadIdx.x, ty = threadIdx.y;
  for (int i=ty;i<32;i+=8) tile[i][tx] = in[(size_t)(r0+i)*C + c0+tx];
  __syncthreads();
  for (int i=ty;i<32;i+=8) out[(size_t)(c0+i)*R + r0+tx] = f2bf(tile[tx][i]);
}

// ---------------- convert f32 -> bf16 flat (both batches) ----------------
__global__ void convX_k(const float* __restrict__ in, u16* __restrict__ out){
  size_t i = ((size_t)blockIdx.x*256 + threadIdx.x) * 8;
  float4 a = *(const float4*)(in + i);
  float4 b = *(const float4*)(in + i + 4);
  ushort4 lo = { f2bf(a.x), f2bf(a.y), f2bf(a.z), f2bf(a.w) };
  ushort4 hi = { f2bf(b.x), f2bf(b.y), f2bf(b.z), f2bf(b.w) };
  *(ushort4*)(out + i)     = lo;
  *(ushort4*)(out + i + 4) = hi;
}

// ---------------- QKV GEMM (m93 bf16 MFMA), both batches: [4096,1024]@[1024,3072]^T ----
// Epilogue splits into Qb[b*16+h][s][64] (x0.125), Kb[...][s][64], Vt[...][d][s].
__global__ __launch_bounds__(256,2) void gemm_qkv_k(
    const u16* __restrict__ A, const u16* __restrict__ Bt,
    const float* __restrict__ bias,
    u16* __restrict__ Qb, u16* __restrict__ Kb, u16* __restrict__ Vt)
{
  const int K = DDIM;
  __shared__ __align__(16) u16 As[128*32];
  __shared__ __align__(16) u16 Bs[128*32];
  const int tid = threadIdx.x;
  const int m0 = blockIdx.x<<7, n0 = blockIdx.y<<7;
  const int w = tid>>6, lane = tid&63, q = lane>>4, ln = lane&15;
  const int wr = (w>>1)<<6, wc = (w&1)<<6;

  f32x4 acc[4][4];
  #pragma unroll
  for (int i=0;i<4;i++)
    #pragma unroll
    for (int j=0;j<4;j++) acc[i][j] = (f32x4){0.f,0.f,0.f,0.f};

  for (int k0=0;k0<K;k0+=32){
    {
      int c = tid, row = c>>2, off = (c&3)<<3;
      *(uint4*)&As[(row<<5)+off] = *(const uint4*)&A [(size_t)(m0+row)*K + k0 + off];
      *(uint4*)&Bs[(row<<5)+off] = *(const uint4*)&Bt[(size_t)(n0+row)*K + k0 + off];
      c = tid + 256; row = c>>2; off = (c&3)<<3;
      *(uint4*)&As[(row<<5)+off] = *(const uint4*)&A [(size_t)(m0+row)*K + k0 + off];
      *(uint4*)&Bs[(row<<5)+off] = *(const uint4*)&Bt[(size_t)(n0+row)*K + k0 + off];
    }
    __syncthreads();
    bf16x8 af[4], bfr[4];
    #pragma unroll
    for (int i=0;i<4;i++) af[i]  = *(const bf16x8*)&As[((wr + (i<<4) + ln)<<5) + (q<<3)];
    #pragma unroll
    for (int j=0;j<4;j++) bfr[j] = *(const bf16x8*)&Bs[((wc + (j<<4) + ln)<<5) + (q<<3)];
    #pragma unroll
    for (int i=0;i<4;i++)
      #pragma unroll
      for (int j=0;j<4;j++)
        acc[i][j] = __builtin_amdgcn_mfma_f32_16x16x32_bf16(af[i], bfr[j], acc[i][j], 0, 0, 0);
    __syncthreads();
  }

  #pragma unroll
  for (int i=0;i<4;i++){
    const int mmb = m0 + wr + (i<<4) + (q<<2);         // global row (4096 range)
    const int bsel = mmb >> 11;                        // batch (uniform per block)
    const int sb   = mmb & 2047;                       // s within batch
    #pragma unroll
    for (int j=0;j<4;j++){
      const int n = n0 + wc + (j<<4) + ln;
      const int h = n / 192;
      const int rr = n - h*192;
      const int bh = (bsel<<4) + h;
      const float bv = bias[n];
      if (rr < 64){                                    // Q, scaled by 1/8
        u16* dst = Qb + (size_t)bh*SS*DEPTH + rr;
        #pragma unroll
        for (int r=0;r<4;r++) dst[(size_t)(sb+r)*DEPTH] = f2bf((acc[i][j][r] + bv)*0.125f);
      } else if (rr < 128){                            // K
        u16* dst = Kb + (size_t)bh*SS*DEPTH + (rr-64);
        #pragma unroll
        for (int r=0;r<4;r++) dst[(size_t)(sb+r)*DEPTH] = f2bf(acc[i][j][r] + bv);
      } else {                                         // V transposed: Vt[bh][d][s]
        ushort4 pv = { f2bf(acc[i][j][0] + bv), f2bf(acc[i][j][1] + bv),
                       f2bf(acc[i][j][2] + bv), f2bf(acc[i][j][3] + bv) };
        *(ushort4*)(Vt + ((size_t)bh*DEPTH + (rr-128))*SS + sb) = pv;
      }
    }
  }
}

// ---------------- MFMA flash attention, causal-balanced q-tile pairs ----------------
// Block = pair of 64-row q-tiles {pi, 31-pi} of one (b,h): constant 33 kv-tiles/block.
// 4 waves x 16 rows. Per kv tile: QK^T (bt vs Ks), register online-softmax,
// P->bf16 via ps (stride 72), PV (bt vs VsT). All LDS strides 72 (2-way = free).
// Output overwrites this block's own Qb rows (sole reader; regs loaded first).
__global__ __launch_bounds__(256,2) void attn_k(
    u16* __restrict__ Qb, const u16* __restrict__ Kb, const u16* __restrict__ Vt)
{
  __shared__ __align__(16) u16 Ks[64*72];      // K tile [j][d], stride 72
  __shared__ __align__(16) u16 VsT[64*72];     // V^T tile [d][j], stride 72
  __shared__ __align__(16) u16 ps[4][16*72];   // per-wave P [m][j], stride 72

  const int tid = threadIdx.x, w = tid>>6, lane = tid&63, q = lane>>4, ln = lane&15;
  const int bh = blockIdx.y;                   // b*16 + h
  const int pi = blockIdx.x;                   // pair index 0..15
  const size_t kbase = (size_t)bh*SS*DEPTH;    // Kb/Qb per-(b,h) base
  const size_t vbase = (size_t)bh*DEPTH*SS;    // Vt per-(b,h) base

  #pragma unroll
  for (int pp=0;pp<2;pp++){
    const int qt = pp ? (31 - pi) : pi;        // q-tile index; T totals 33 per block
    const int r0 = qt<<6;

    bf16x8 qf[2];
    #pragma unroll
    for (int ks=0;ks<2;ks++)
      qf[ks] = *(const bf16x8*)(Qb + kbase + (size_t)(r0 + (w<<4) + ln)*DEPTH + (ks<<5) + (q<<3));

    f32x4 o[4];
    #pragma unroll
    for (int nt=0;nt<4;nt++) o[nt] = (f32x4){0.f,0.f,0.f,0.f};
    float m_r[4], l_r[4];
    #pragma unroll
    for (int r=0;r<4;r++){ m_r[r] = NEG_BIG; l_r[r] = 0.f; }

    const int T = qt + 1;
    for (int t=0;t<T;t++){
      __syncthreads();                         // prior tile's Ks/VsT/ps reads done
      #pragma unroll
      for (int p=0;p<2;p++){
        int e = (p*256 + tid)*8;
        int j = e>>6, d = e&63;
        *(uint4*)&Ks[j*72 + d]   = *(const uint4*)(Kb + kbase + (size_t)((t<<6)+j)*DEPTH + d);
        *(uint4*)&VsT[j*72 + d]  = *(const uint4*)(Vt + vbase + (size_t)j*SS + (t<<6) + d);
      }
      __syncthreads();

      // QK^T
      f32x4 sc[4];
      #pragma unroll
      for (int jt=0;jt<4;jt++) sc[jt] = (f32x4){0.f,0.f,0.f,0.f};
      #pragma unroll
      for (int ks=0;ks<2;ks++){
        #pragma unroll
        for (int jt=0;jt<4;jt++){
          bf16x8 kf = *(const bf16x8*)&Ks[((jt<<4)+ln)*72 + (ks<<5) + (q<<3)];
          sc[jt] = __builtin_amdgcn_mfma_f32_16x16x32_bf16(qf[ks], kf, sc[jt], 0, 0, 0);
        }
      }

      // causal mask on diagonal tile
      if (t == T-1){
        const int rowb = r0 + (w<<4) + (q<<2);
        #pragma unroll
        for (int jt=0;jt<4;jt++){
          const int col = (t<<6) + (jt<<4) + ln;
          #pragma unroll
          for (int r=0;r<4;r++)
            if (col > rowb + r) sc[jt][r] = NEG_BIG;
        }
      }

      // online softmax per row (row lives on 16 lanes sharing quad q)
      float alpha_r[4];
      #pragma unroll
      for (int r=0;r<4;r++){
        float mt = fmaxf(fmaxf(sc[0][r], sc[1][r]), fmaxf(sc[2][r], sc[3][r]));
        #pragma unroll
        for (int off=1; off<16; off<<=1) mt = fmaxf(mt, __shfl_xor(mt, off));
        const float mnew = fmaxf(m_r[r], mt);
        alpha_r[r] = __expf(m_r[r] - mnew);
        float p0 = __expf(sc[0][r]-mnew), p1 = __expf(sc[1][r]-mnew);
        float p2 = __expf(sc[2][r]-mnew), p3 = __expf(sc[3][r]-mnew);
        const int mrow = (q<<2) + r;
        ps[w][mrow*72 +      ln] = f2bf(p0);
        ps[w][mrow*72 + 16 + ln] = f2bf(p1);
        ps[w][mrow*72 + 32 + ln] = f2bf(p2);
        ps[w][mrow*72 + 48 + ln] = f2bf(p3);
        float psum = (p0+p1)+(p2+p3);
        #pragma unroll
        for (int off=1; off<16; off<<=1) psum += __shfl_xor(psum, off);
        l_r[r] = l_r[r]*alpha_r[r] + psum;
        m_r[r] = mnew;
      }
      #pragma unroll
      for (int nt=0;nt<4;nt++)
        #pragma unroll
        for (int r=0;r<4;r++) o[nt][r] *= alpha_r[r];

      __syncthreads();                         // ps visible/ordered before PV reads

      // PV
      #pragma unroll
      for (int ks=0;ks<2;ks++){
        bf16x8 pa = *(const bf16x8*)&ps[w][ln*72 + (ks<<5) + (q<<3)];
        #pragma unroll
        for (int nt=0;nt<4;nt++){
          bf16x8 vf = *(const bf16x8*)&VsT[((nt<<4)+ln)*72 + (ks<<5) + (q<<3)];
          o[nt] = __builtin_amdgcn_mfma_f32_16x16x32_bf16(pa, vf, o[nt], 0, 0, 0);
        }
      }
    }

    // epilogue: o/l -> bf16, overwrite this block's own Qb rows
    #pragma unroll
    for (int r=0;r<4;r++){
      const float rl = 1.f / fmaxf(l_r[r], 1e-30f);
      const int s = r0 + (w<<4) + (q<<2) + r;
      #pragma unroll
      for (int nt=0;nt<4;nt++)
        Qb[kbase + (size_t)s*DEPTH + (nt<<4) + ln] = f2bf(o[nt][r] * rl);
    }
  }
}

// ---------------- out projection (m93 bf16 MFMA), both batches, f32 out ----------------
// A(m,k) = Qb[(m>>11)*16 + k/64][m&2047][k%64]
__global__ __launch_bounds__(256,2) void gemm_out_k(
    const u16* __restrict__ Aq, const u16* __restrict__ Bt,
    const float* __restrict__ bias, float* __restrict__ out)
{
  const int K = DDIM;
  __shared__ __align__(16) u16 As[128*32];
  __shared__ __align__(16) u16 Bs[128*32];
  const int tid = threadIdx.x;
  const int m0 = blockIdx.x<<7, n0 = blockIdx.y<<7;
  const int bsel = m0>>11, ms = m0&2047;       // batch select (uniform per block)
  const int w = tid>>6, lane = tid&63, q = lane>>4, ln = lane&15;
  const int wr = (w>>1)<<6, wc = (w&1)<<6;

  f32x4 acc[4][4];
  #pragma unroll
  for (int i=0;i<4;i++)
    #pragma unroll
    for (int j=0;j<4;j++) acc[i][j] = (f32x4){0.f,0.f,0.f,0.f};

  for (int k0=0;k0<K;k0+=32){
    const size_t abase = (size_t)((bsel<<4) + (k0>>6))*SS*DEPTH + (k0&63);
    {
      int c = tid, row = c>>2, off = (c&3)<<3;
      *(uint4*)&As[(row<<5)+off] = *(const uint4*)&Aq[abase + (size_t)(ms+row)*DEPTH + off];
      *(uint4*)&Bs[(row<<5)+off] = *(const uint4*)&Bt[(size_t)(n0+row)*K + k0 + off];
      c = tid + 256; row = c>>2; off = (c&3)<<3;
      *(uint4*)&As[(row<<5)+off] = *(const uint4*)&Aq[abase + (size_t)(ms+row)*DEPTH + off];
      *(uint4*)&Bs[(row<<5)+off] = *(const uint4*)&Bt[(size_t)(n0+row)*K + k0 + off];
    }
    __syncthreads();
    bf16x8 af[4], bfr[4];
    #pragma unroll
    for (int i=0;i<4;i++) af[i]  = *(const bf16x8*)&As[((wr + (i<<4) + ln)<<5) + (q<<3)];
    #pragma unroll
    for (int j=0;j<4;j++) bfr[j] = *(const bf16x8*)&Bs[((wc + (j<<4) + ln)<<5) + (q<<3)];
    #pragma unroll
    for (int i=0;i<4;i++)
      #pragma unroll
      for (int j=0;j<4;j++)
        acc[i][j] = __builtin_amdgcn_mfma_f32_16x16x32_bf16(af[i], bfr[j], acc[i][j], 0, 0, 0);
    __syncthreads();
  }

  #pragma unroll
  for (int i=0;i<4;i++){
    #pragma unroll
    for (int j=0;j<4;j++){
      const int n = n0 + wc + (j<<4) + ln;
      const float bv = bias[n];
      #pragma unroll
      for (int r=0;r<4;r++){
        const int mm = m0 + wr + (i<<4) + (q<<2) + r;
        out[(size_t)mm*DDIM + n] = acc[i][j][r] + bv;
      }
    }
  }
}

extern "C" void kernel_launch(void* const* d_in, const int* in_sizes, int n_in,
                              void* d_out, int out_size, void* d_ws, size_t ws_size,
                              hipStream_t stream)
{
  int ix = 0, iw = 2, ibq = 3, iwo = 4, ibo = 5;
  if (n_in == 5){ iw = 1; ibq = 2; iwo = 3; ibo = 4; }
  const float* x  = (const float*)d_in[ix];
  const float* Wq = (const float*)d_in[iw];
  const float* bq = (const float*)d_in[ibq];
  const float* Wo = (const float*)d_in[iwo];
  const float* bo = (const float*)d_in[ibo];
  float* out = (float*)d_out;

  // workspace (u16 units), total 41,943,040 B — equals the round-1-proven footprint
  u16* ws  = (u16*)d_ws;
  u16* Wqt = ws;                                   // [3072,1024] bf16
  u16* Wot = Wqt + (size_t)QKVN*DDIM;              // [1024,1024] bf16 (bt form)
  u16* Qb  = Wot + (size_t)DDIM*DDIM;              // [B*H][S][64]; attn out aliases here
  u16* Kb  = Qb  + (size_t)BB*HH*SS*DEPTH;         // [B*H][S][64]
  u16* Vt  = Kb  + (size_t)BB*HH*SS*DEPTH;         // [B*H][64][S] (V transposed)
  u16* xb  = Vt  + (size_t)BB*HH*SS*DEPTH;         // [2,2048,1024] bf16

  convT_k<<<dim3(QKVN/32, DDIM/32), dim3(32,8), 0, stream>>>(Wq, Wqt, DDIM, QKVN);
  convT_k<<<dim3(DDIM/32, DDIM/32), dim3(32,8), 0, stream>>>(Wo, Wot, DDIM, DDIM);
  convX_k<<<dim3(BB*SS*DDIM/2048), 256, 0, stream>>>(x, xb);

  gemm_qkv_k<<<dim3(BB*SS/128, QKVN/128), 256, 0, stream>>>(xb, Wqt, bq, Qb, Kb, Vt);
  attn_k    <<<dim3(16, BB*HH),           256, 0, stream>>>(Qb, Kb, Vt);
  gemm_out_k<<<dim3(BB*SS/128, DDIM/128), 256, 0, stream>>>(Qb, Wot, bo, out);
}

// Round 9
// 236.908 us; speedup vs baseline: 8.6638x; 1.0714x over previous
//
#include <hip/hip_runtime.h>

#define BB 2
#define SS 2048
#define DDIM 1024
#define HH 16
#define DEPTH 64
#define QKVN (3*DDIM)

typedef unsigned short u16;
typedef unsigned int u32;
typedef __attribute__((ext_vector_type(8))) short bf16x8;
typedef __attribute__((ext_vector_type(4))) float f32x4;

__device__ __forceinline__ u16 f2bf(float f){
  union{float f; u32 u;} z; z.f=f;
  u32 r = z.u + 0x7fffu + ((z.u>>16)&1u);
  return (u16)(r>>16);
}
#define NEG_BIG (-1e30f)

// ---------------- transpose+convert f32 [R,C] -> bf16 [C,R] ----------------
__global__ void convT_k(const float* __restrict__ in, u16* __restrict__ out, int R, int C){
  __shared__ float tile[32][33];
  int c0 = blockIdx.x<<5, r0 = blockIdx.y<<5;
  int tx = threadIdx.x, ty = threadIdx.y;
  for (int i=ty;i<32;i+=8) tile[i][tx] = in[(size_t)(r0+i)*C + c0+tx];
  __syncthreads();
  for (int i=ty;i<32;i+=8) out[(size_t)(c0+i)*R + r0+tx] = f2bf(tile[tx][i]);
}

// ---------------- convert f32 -> bf16 flat (both batches) ----------------
__global__ void convX_k(const float* __restrict__ in, u16* __restrict__ out){
  size_t i = ((size_t)blockIdx.x*256 + threadIdx.x) * 8;
  float4 a = *(const float4*)(in + i);
  float4 b = *(const float4*)(in + i + 4);
  ushort4 lo = { f2bf(a.x), f2bf(a.y), f2bf(a.z), f2bf(a.w) };
  ushort4 hi = { f2bf(b.x), f2bf(b.y), f2bf(b.z), f2bf(b.w) };
  *(ushort4*)(out + i)     = lo;
  *(ushort4*)(out + i + 4) = hi;
}

// ---------------- QKV GEMM (m93 bf16 MFMA), both batches: [4096,1024]@[1024,3072]^T ----
// Epilogue splits into Qb[b*16+h][s][64] (x0.125), Kb[...][s][64], Vt[...][d][s].
__global__ __launch_bounds__(256,2) void gemm_qkv_k(
    const u16* __restrict__ A, const u16* __restrict__ Bt,
    const float* __restrict__ bias,
    u16* __restrict__ Qb, u16* __restrict__ Kb, u16* __restrict__ Vt)
{
  const int K = DDIM;
  __shared__ __align__(16) u16 As[128*32];
  __shared__ __align__(16) u16 Bs[128*32];
  const int tid = threadIdx.x;
  const int m0 = blockIdx.x<<7, n0 = blockIdx.y<<7;
  const int w = tid>>6, lane = tid&63, q = lane>>4, ln = lane&15;
  const int wr = (w>>1)<<6, wc = (w&1)<<6;

  f32x4 acc[4][4];
  #pragma unroll
  for (int i=0;i<4;i++)
    #pragma unroll
    for (int j=0;j<4;j++) acc[i][j] = (f32x4){0.f,0.f,0.f,0.f};

  for (int k0=0;k0<K;k0+=32){
    {
      int c = tid, row = c>>2, off = (c&3)<<3;
      *(uint4*)&As[(row<<5)+off] = *(const uint4*)&A [(size_t)(m0+row)*K + k0 + off];
      *(uint4*)&Bs[(row<<5)+off] = *(const uint4*)&Bt[(size_t)(n0+row)*K + k0 + off];
      c = tid + 256; row = c>>2; off = (c&3)<<3;
      *(uint4*)&As[(row<<5)+off] = *(const uint4*)&A [(size_t)(m0+row)*K + k0 + off];
      *(uint4*)&Bs[(row<<5)+off] = *(const uint4*)&Bt[(size_t)(n0+row)*K + k0 + off];
    }
    __syncthreads();
    bf16x8 af[4], bfr[4];
    #pragma unroll
    for (int i=0;i<4;i++) af[i]  = *(const bf16x8*)&As[((wr + (i<<4) + ln)<<5) + (q<<3)];
    #pragma unroll
    for (int j=0;j<4;j++) bfr[j] = *(const bf16x8*)&Bs[((wc + (j<<4) + ln)<<5) + (q<<3)];
    #pragma unroll
    for (int i=0;i<4;i++)
      #pragma unroll
      for (int j=0;j<4;j++)
        acc[i][j] = __builtin_amdgcn_mfma_f32_16x16x32_bf16(af[i], bfr[j], acc[i][j], 0, 0, 0);
    __syncthreads();
  }

  #pragma unroll
  for (int i=0;i<4;i++){
    const int mmb = m0 + wr + (i<<4) + (q<<2);         // global row (4096 range)
    const int bsel = mmb >> 11;                        // batch (uniform per block)
    const int sb   = mmb & 2047;                       // s within batch
    #pragma unroll
    for (int j=0;j<4;j++){
      const int n = n0 + wc + (j<<4) + ln;
      const int h = n / 192;
      const int rr = n - h*192;
      const int bh = (bsel<<4) + h;
      const float bv = bias[n];
      if (rr < 64){                                    // Q, scaled by 1/8
        u16* dst = Qb + (size_t)bh*SS*DEPTH + rr;
        #pragma unroll
        for (int r=0;r<4;r++) dst[(size_t)(sb+r)*DEPTH] = f2bf((acc[i][j][r] + bv)*0.125f);
      } else if (rr < 128){                            // K
        u16* dst = Kb + (size_t)bh*SS*DEPTH + (rr-64);
        #pragma unroll
        for (int r=0;r<4;r++) dst[(size_t)(sb+r)*DEPTH] = f2bf(acc[i][j][r] + bv);
      } else {                                         // V transposed: Vt[bh][d][s]
        ushort4 pv = { f2bf(acc[i][j][0] + bv), f2bf(acc[i][j][1] + bv),
                       f2bf(acc[i][j][2] + bv), f2bf(acc[i][j][3] + bv) };
        *(ushort4*)(Vt + ((size_t)bh*DEPTH + (rr-128))*SS + sb) = pv;
      }
    }
  }
}

// ---------------- MFMA flash attention, occupancy-tuned ----------------
// Grid (32 bh, 32 slots), one 64-row q-tile per block, 4 blocks/CU fully resident.
// Slot->qt permutation keeps per-CU total tile-work constant under id-mod-8 XCD
// round-robin: slots {y, y+8, y+16, y+24} -> qt {31-r, 16+r, 15-r, r} (sum 62).
// bh on blockIdx.x => all 32 blocks of a head land on XCD bh%8 (K/V fits its L2).
__global__ __launch_bounds__(256,4) void attn_k(
    u16* __restrict__ Qb, const u16* __restrict__ Kb, const u16* __restrict__ Vt)
{
  __shared__ __align__(16) u16 Ks[64*72];      // K tile [j][d], stride 72
  __shared__ __align__(16) u16 VsT[64*72];     // V^T tile [d][j], stride 72
  __shared__ __align__(16) u16 ps[4][16*72];   // per-wave P [m][j], stride 72

  const int tid = threadIdx.x, w = tid>>6, lane = tid&63, q = lane>>4, ln = lane&15;
  const int bh = blockIdx.x;                   // b*16 + h  (XCD = bh%8)
  const int y  = blockIdx.y, sgrp = y>>3, rr_ = y&7;
  const int qt = (sgrp==0) ? 31-rr_ : (sgrp==1) ? 16+rr_ : (sgrp==2) ? 15-rr_ : rr_;
  const int r0 = qt<<6;
  const size_t kbase = (size_t)bh*SS*DEPTH;    // Kb/Qb per-(b,h) base
  const size_t vbase = (size_t)bh*DEPTH*SS;    // Vt per-(b,h) base

  bf16x8 qf[2];
  #pragma unroll
  for (int ks=0;ks<2;ks++)
    qf[ks] = *(const bf16x8*)(Qb + kbase + (size_t)(r0 + (w<<4) + ln)*DEPTH + (ks<<5) + (q<<3));

  f32x4 o[4];
  #pragma unroll
  for (int nt=0;nt<4;nt++) o[nt] = (f32x4){0.f,0.f,0.f,0.f};
  float m_r[4], l_r[4];
  #pragma unroll
  for (int r=0;r<4;r++){ m_r[r] = NEG_BIG; l_r[r] = 0.f; }

  const int T = qt + 1;
  for (int t=0;t<T;t++){
    __syncthreads();                           // prior tile's Ks/VsT/ps reads done
    #pragma unroll
    for (int p=0;p<2;p++){
      int e = (p*256 + tid)*8;
      int j = e>>6, d = e&63;
      *(uint4*)&Ks[j*72 + d]   = *(const uint4*)(Kb + kbase + (size_t)((t<<6)+j)*DEPTH + d);
      *(uint4*)&VsT[j*72 + d]  = *(const uint4*)(Vt + vbase + (size_t)j*SS + (t<<6) + d);
    }
    __syncthreads();

    // QK^T
    f32x4 sc[4];
    #pragma unroll
    for (int jt=0;jt<4;jt++) sc[jt] = (f32x4){0.f,0.f,0.f,0.f};
    #pragma unroll
    for (int ks=0;ks<2;ks++){
      #pragma unroll
      for (int jt=0;jt<4;jt++){
        bf16x8 kf = *(const bf16x8*)&Ks[((jt<<4)+ln)*72 + (ks<<5) + (q<<3)];
        sc[jt] = __builtin_amdgcn_mfma_f32_16x16x32_bf16(qf[ks], kf, sc[jt], 0, 0, 0);
      }
    }

    // causal mask on diagonal tile
    if (t == T-1){
      const int rowb = r0 + (w<<4) + (q<<2);
      #pragma unroll
      for (int jt=0;jt<4;jt++){
        const int col = (t<<6) + (jt<<4) + ln;
        #pragma unroll
        for (int r=0;r<4;r++)
          if (col > rowb + r) sc[jt][r] = NEG_BIG;
      }
    }

    // online softmax per row (row lives on 16 lanes sharing quad q)
    float alpha_r[4];
    #pragma unroll
    for (int r=0;r<4;r++){
      float mt = fmaxf(fmaxf(sc[0][r], sc[1][r]), fmaxf(sc[2][r], sc[3][r]));
      #pragma unroll
      for (int off=1; off<16; off<<=1) mt = fmaxf(mt, __shfl_xor(mt, off));
      const float mnew = fmaxf(m_r[r], mt);
      alpha_r[r] = __expf(m_r[r] - mnew);
      float p0 = __expf(sc[0][r]-mnew), p1 = __expf(sc[1][r]-mnew);
      float p2 = __expf(sc[2][r]-mnew), p3 = __expf(sc[3][r]-mnew);
      const int mrow = (q<<2) + r;
      ps[w][mrow*72 +      ln] = f2bf(p0);
      ps[w][mrow*72 + 16 + ln] = f2bf(p1);
      ps[w][mrow*72 + 32 + ln] = f2bf(p2);
      ps[w][mrow*72 + 48 + ln] = f2bf(p3);
      float psum = (p0+p1)+(p2+p3);
      #pragma unroll
      for (int off=1; off<16; off<<=1) psum += __shfl_xor(psum, off);
      l_r[r] = l_r[r]*alpha_r[r] + psum;
      m_r[r] = mnew;
    }
    #pragma unroll
    for (int nt=0;nt<4;nt++)
      #pragma unroll
      for (int r=0;r<4;r++) o[nt][r] *= alpha_r[r];

    __syncthreads();                           // ps visible/ordered before PV reads

    // PV
    #pragma unroll
    for (int ks=0;ks<2;ks++){
      bf16x8 pa = *(const bf16x8*)&ps[w][ln*72 + (ks<<5) + (q<<3)];
      #pragma unroll
      for (int nt=0;nt<4;nt++){
        bf16x8 vf = *(const bf16x8*)&VsT[((nt<<4)+ln)*72 + (ks<<5) + (q<<3)];
        o[nt] = __builtin_amdgcn_mfma_f32_16x16x32_bf16(pa, vf, o[nt], 0, 0, 0);
      }
    }
  }

  // epilogue: o/l -> bf16, overwrite this block's own Qb rows
  #pragma unroll
  for (int r=0;r<4;r++){
    const float rl = 1.f / fmaxf(l_r[r], 1e-30f);
    const int s = r0 + (w<<4) + (q<<2) + r;
    #pragma unroll
    for (int nt=0;nt<4;nt++)
      Qb[kbase + (size_t)s*DEPTH + (nt<<4) + ln] = f2bf(o[nt][r] * rl);
  }
}

// ---------------- out projection (m93 bf16 MFMA), both batches, f32 out ----------------
// A(m,k) = Qb[(m>>11)*16 + k/64][m&2047][k%64]
__global__ __launch_bounds__(256,2) void gemm_out_k(
    const u16* __restrict__ Aq, const u16* __restrict__ Bt,
    const float* __restrict__ bias, float* __restrict__ out)
{
  const int K = DDIM;
  __shared__ __align__(16) u16 As[128*32];
  __shared__ __align__(16) u16 Bs[128*32];
  const int tid = threadIdx.x;
  const int m0 = blockIdx.x<<7, n0 = blockIdx.y<<7;
  const int bsel = m0>>11, ms = m0&2047;       // batch select (uniform per block)
  const int w = tid>>6, lane = tid&63, q = lane>>4, ln = lane&15;
  const int wr = (w>>1)<<6, wc = (w&1)<<6;

  f32x4 acc[4][4];
  #pragma unroll
  for (int i=0;i<4;i++)
    #pragma unroll
    for (int j=0;j<4;j++) acc[i][j] = (f32x4){0.f,0.f,0.f,0.f};

  for (int k0=0;k0<K;k0+=32){
    const size_t abase = (size_t)((bsel<<4) + (k0>>6))*SS*DEPTH + (k0&63);
    {
      int c = tid, row = c>>2, off = (c&3)<<3;
      *(uint4*)&As[(row<<5)+off] = *(const uint4*)&Aq[abase + (size_t)(ms+row)*DEPTH + off];
      *(uint4*)&Bs[(row<<5)+off] = *(const uint4*)&Bt[(size_t)(n0+row)*K + k0 + off];
      c = tid + 256; row = c>>2; off = (c&3)<<3;
      *(uint4*)&As[(row<<5)+off] = *(const uint4*)&Aq[abase + (size_t)(ms+row)*DEPTH + off];
      *(uint4*)&Bs[(row<<5)+off] = *(const uint4*)&Bt[(size_t)(n0+row)*K + k0 + off];
    }
    __syncthreads();
    bf16x8 af[4], bfr[4];
    #pragma unroll
    for (int i=0;i<4;i++) af[i]  = *(const bf16x8*)&As[((wr + (i<<4) + ln)<<5) + (q<<3)];
    #pragma unroll
    for (int j=0;j<4;j++) bfr[j] = *(const bf16x8*)&Bs[((wc + (j<<4) + ln)<<5) + (q<<3)];
    #pragma unroll
    for (int i=0;i<4;i++)
      #pragma unroll
      for (int j=0;j<4;j++)
        acc[i][j] = __builtin_amdgcn_mfma_f32_16x16x32_bf16(af[i], bfr[j], acc[i][j], 0, 0, 0);
    __syncthreads();
  }

  #pragma unroll
  for (int i=0;i<4;i++){
    #pragma unroll
    for (int j=0;j<4;j++){
      const int n = n0 + wc + (j<<4) + ln;
      const float bv = bias[n];
      #pragma unroll
      for (int r=0;r<4;r++){
        const int mm = m0 + wr + (i<<4) + (q<<2) + r;
        out[(size_t)mm*DDIM + n] = acc[i][j][r] + bv;
      }
    }
  }
}

extern "C" void kernel_launch(void* const* d_in, const int* in_sizes, int n_in,
                              void* d_out, int out_size, void* d_ws, size_t ws_size,
                              hipStream_t stream)
{
  int ix = 0, iw = 2, ibq = 3, iwo = 4, ibo = 5;
  if (n_in == 5){ iw = 1; ibq = 2; iwo = 3; ibo = 4; }
  const float* x  = (const float*)d_in[ix];
  const float* Wq = (const float*)d_in[iw];
  const float* bq = (const float*)d_in[ibq];
  const float* Wo = (const float*)d_in[iwo];
  const float* bo = (const float*)d_in[ibo];
  float* out = (float*)d_out;

  // workspace (u16 units), total 41,943,040 B — round-1-proven footprint
  u16* ws  = (u16*)d_ws;
  u16* Wqt = ws;                                   // [3072,1024] bf16
  u16* Wot = Wqt + (size_t)QKVN*DDIM;              // [1024,1024] bf16 (bt form)
  u16* Qb  = Wot + (size_t)DDIM*DDIM;              // [B*H][S][64]; attn out aliases here
  u16* Kb  = Qb  + (size_t)BB*HH*SS*DEPTH;         // [B*H][S][64]
  u16* Vt  = Kb  + (size_t)BB*HH*SS*DEPTH;         // [B*H][64][S] (V transposed)
  u16* xb  = Vt  + (size_t)BB*HH*SS*DEPTH;         // [2,2048,1024] bf16

  convT_k<<<dim3(QKVN/32, DDIM/32), dim3(32,8), 0, stream>>>(Wq, Wqt, DDIM, QKVN);
  convT_k<<<dim3(DDIM/32, DDIM/32), dim3(32,8), 0, stream>>>(Wo, Wot, DDIM, DDIM);
  convX_k<<<dim3(BB*SS*DDIM/2048), 256, 0, stream>>>(x, xb);

  gemm_qkv_k<<<dim3(BB*SS/128, QKVN/128), 256, 0, stream>>>(xb, Wqt, bq, Qb, Kb, Vt);
  attn_k    <<<dim3(BB*HH, 32),           256, 0, stream>>>(Qb, Kb, Vt);
  gemm_out_k<<<dim3(BB*SS/128, DDIM/128), 256, 0, stream>>>(Qb, Wot, bo, out);
}